// Round 4
// baseline (5493.314 us; speedup 1.0000x reference)
//
#include <hip/hip_runtime.h>

typedef __attribute__((ext_vector_type(8))) short bf16x8;
typedef __attribute__((ext_vector_type(4))) float f32x4;
typedef __attribute__((ext_vector_type(2))) float f32x2;

constexpr int   HD      = 128;
constexpr float T_NEAR  = 0.2f;
constexpr float T_FAR   = 2.0f;
constexpr float ALPHA_C = 100.0f;
constexpr int   MARCH_N = 32;
constexpr float HIT_EPS = 0.005f;
constexpr int   TP_N    = 32;
constexpr float STEP    = 0.0634765625f;  // (2.0 + 0.5*(2/32))/32, exact

// ---------- bf16 helpers ----------
__device__ __forceinline__ unsigned short f2bf(float x) {
  unsigned u = __float_as_uint(x);
  unsigned r = 0x7fffu + ((u >> 16) & 1u);
  return (unsigned short)((u + r) >> 16);
}

union U8 { bf16x8 v; uint4 u4; unsigned short us[8]; };

__device__ __forceinline__ f32x2 pk_fma(f32x2 a, f32x2 b, f32x2 c) {
  f32x2 d;
  asm("v_pk_fma_f32 %0, %1, %2, %3" : "=v"(d) : "v"(a), "v"(b), "v"(c));
  return d;
}

// {h.x,h.y} -> packed bf16 pair (round-half-up) with relu in bf16-bit domain.
__device__ __forceinline__ unsigned pack_relu_pair(f32x2 h) {
  unsigned u0 = __float_as_uint(h.x) + 0x8000u;
  unsigned u1 = __float_as_uint(h.y) + 0x8000u;
  unsigned w, r;
  asm("v_perm_b32 %0, %1, %2, %3" : "=v"(w) : "v"(u1), "v"(u0), "s"(0x07060302u));
  asm("v_pk_max_i16 %0, %1, %2" : "=v"(r) : "v"(w), "v"(0u));
  return r;
}

// ---------- setup kernel: pack W2^T into per-lane MFMA A-fragments ----------
__global__ void pack_w2(const float* __restrict__ W2,
                        unsigned short* __restrict__ hi,
                        unsigned short* __restrict__ lo) {
  int idx = blockIdx.x * 256 + threadIdx.x;     // 0..16383
  int j = idx & 7, l = (idx >> 3) & 63, t = (idx >> 9) & 7, s = idx >> 12;
  int m = 16 * t + (l & 15);
  int k = 32 * s + (l >> 4) * 8 + j;
  float w = W2[k * HD + m];
  unsigned short h = f2bf(w);
  float hf = __uint_as_float(((unsigned)h) << 16);
  hi[idx] = h;
  lo[idx] = f2bf(w - hf);
}

// ---------- fast bf16 MFMA SDF eval (regs + tiny LDS tables) ----------
__device__ __forceinline__ float sdf_fast(float t,
    const bf16x8 (&w2f)[4][8], const f32x2 (&ap)[16], const f32x2 (&cp)[16],
    const f32x4* __restrict__ sB2q, const float4* __restrict__ sW3q, float b3v)
{
  f32x2 t2; t2.x = t; t2.y = t;

  // C-init = b2 fragments straight from LDS (broadcast within quad)
  f32x4 acc[8];
  #pragma unroll
  for (int u = 0; u < 8; ++u) acc[u] = sB2q[u];

  // interleave B-build (VALU) with MFMA octets
  #pragma unroll
  for (int s = 0; s < 4; ++s) {
    U8 B;
    B.u4.x = pack_relu_pair(pk_fma(cp[4*s+0], t2, ap[4*s+0]));
    B.u4.y = pack_relu_pair(pk_fma(cp[4*s+1], t2, ap[4*s+1]));
    B.u4.z = pack_relu_pair(pk_fma(cp[4*s+2], t2, ap[4*s+2]));
    B.u4.w = pack_relu_pair(pk_fma(cp[4*s+3], t2, ap[4*s+3]));
    #pragma unroll
    for (int u = 0; u < 8; ++u)
      acc[u] = __builtin_amdgcn_mfma_f32_16x16x32_bf16(w2f[s][u], B.v, acc[u], 0, 0, 0);
  }

  f32x2 e0; e0.x = 0.f; e0.y = 0.f;
  f32x2 e1 = e0, e2 = e0, e3 = e0;
  #pragma unroll
  for (int u = 0; u < 8; ++u) {
    float4 wv = sW3q[u];
    f32x4 y = acc[u];
    f32x2 lo; lo.x = fmaxf(y.x, 0.f); lo.y = fmaxf(y.y, 0.f);
    f32x2 hi; hi.x = fmaxf(y.z, 0.f); hi.y = fmaxf(y.w, 0.f);
    f32x2 wa; wa.x = wv.x; wa.y = wv.y;
    f32x2 wb; wb.x = wv.z; wb.y = wv.w;
    if (u & 1) { e2 = pk_fma(lo, wa, e2); e3 = pk_fma(hi, wb, e3); }
    else       { e0 = pk_fma(lo, wa, e0); e1 = pk_fma(hi, wb, e1); }
  }
  float d = (e0.x + e0.y) + (e1.x + e1.y) + ((e2.x + e2.y) + (e3.x + e3.y));
  d += __shfl_xor(d, 16);
  d += __shfl_xor(d, 32);
  return d + b3v;
}

// ---------- hi/lo-split precise eval (x100 tput channel) ----------
__device__ float sdf_precise(float t, int lane,
    const bf16x8 (&w2f)[4][8], const f32x2 (&ap)[16], const f32x2 (&cp)[16],
    const f32x4* __restrict__ sB2q, const float4* __restrict__ sW3q, float b3v,
    const unsigned short* __restrict__ wlo)
{
  U8 HH[4], HL[4];
  #pragma unroll
  for (int s = 0; s < 4; ++s) {
    #pragma unroll
    for (int p = 0; p < 4; ++p) {
      float h0 = fmaxf(fmaf(cp[4*s+p].x, t, ap[4*s+p].x), 0.f);
      float h1 = fmaxf(fmaf(cp[4*s+p].y, t, ap[4*s+p].y), 0.f);
      unsigned short hb0 = f2bf(h0), hb1 = f2bf(h1);
      float r0 = h0 - __uint_as_float(((unsigned)hb0) << 16);
      float r1 = h1 - __uint_as_float(((unsigned)hb1) << 16);
      HH[s].us[2*p]     = hb0;      HH[s].us[2*p + 1] = hb1;
      HL[s].us[2*p]     = f2bf(r0); HL[s].us[2*p + 1] = f2bf(r1);
    }
  }

  const bf16x8* wloF = (const bf16x8*)wlo;
  f32x4 acc[8];
  #pragma unroll
  for (int u = 0; u < 8; ++u) acc[u] = sB2q[u];
  #pragma unroll
  for (int s = 0; s < 4; ++s) {
    #pragma unroll
    for (int u = 0; u < 8; ++u) {
      bf16x8 wl = wloF[(s * 8 + u) * 64 + lane];
      acc[u] = __builtin_amdgcn_mfma_f32_16x16x32_bf16(w2f[s][u], HH[s].v, acc[u], 0, 0, 0);
      acc[u] = __builtin_amdgcn_mfma_f32_16x16x32_bf16(wl,        HH[s].v, acc[u], 0, 0, 0);
      acc[u] = __builtin_amdgcn_mfma_f32_16x16x32_bf16(w2f[s][u], HL[s].v, acc[u], 0, 0, 0);
    }
  }

  f32x2 e0; e0.x = 0.f; e0.y = 0.f;
  f32x2 e1 = e0, e2 = e0, e3 = e0;
  #pragma unroll
  for (int u = 0; u < 8; ++u) {
    float4 wv = sW3q[u];
    f32x4 y = acc[u];
    f32x2 lo; lo.x = fmaxf(y.x, 0.f); lo.y = fmaxf(y.y, 0.f);
    f32x2 hi; hi.x = fmaxf(y.z, 0.f); hi.y = fmaxf(y.w, 0.f);
    f32x2 wa; wa.x = wv.x; wa.y = wv.y;
    f32x2 wb; wb.x = wv.z; wb.y = wv.w;
    if (u & 1) { e2 = pk_fma(lo, wa, e2); e3 = pk_fma(hi, wb, e3); }
    else       { e0 = pk_fma(lo, wa, e0); e1 = pk_fma(hi, wb, e1); }
  }
  float d = (e0.x + e0.y) + (e1.x + e1.y) + ((e2.x + e2.y) + (e3.x + e3.y));
  d += __shfl_xor(d, 16);
  d += __shfl_xor(d, 32);
  return d + b3v;
}

// ---------- main: 1 wave = 16 rays, 2 waves/SIMD target ----------
__global__ __launch_bounds__(256, 2)
void render(const float* __restrict__ rays,
            const float* __restrict__ W1, const float* __restrict__ b1,
            const float* __restrict__ b2, const float* __restrict__ W3,
            const float* __restrict__ b3,
            const float* __restrict__ R1, const float* __restrict__ rb1,
            const float* __restrict__ R2, const float* __restrict__ rb2,
            const unsigned short* __restrict__ whi,
            const unsigned short* __restrict__ wlo,
            float* __restrict__ out, int nrays)
{
  // tiny broadcast tables: b2 fragments + W3 pairs, per quad (1 KB total)
  __shared__ float4 sB2[32];
  __shared__ float4 sW3[32];
  const int tid  = threadIdx.x;
  if (tid < 32) {
    int u = tid & 7, qq = tid >> 3;
    int n0 = 16 * u + 4 * qq;
    sB2[tid] = *(const float4*)(b2 + n0);
    sW3[tid] = *(const float4*)(W3 + n0);
  }
  __syncthreads();

  const int lane = tid & 63;
  const int q    = lane >> 4;
  const int wv   = tid >> 6;
  const int ray  = blockIdx.x * 64 + wv * 16 + (lane & 15);

  const f32x4*  sB2q = (const f32x4*)(sB2 + q * 8);
  const float4* sW3q = sW3 + q * 8;

  // W2^T hi fragments resident: 128 VGPRs
  bf16x8 w2f[4][8];
  const bf16x8* whiF = (const bf16x8*)whi;
  #pragma unroll
  for (int s = 0; s < 4; ++s)
    #pragma unroll
    for (int u = 0; u < 8; ++u)
      w2f[s][u] = whiF[(s * 8 + u) * 64 + lane];

  const float rox = rays[ray * 6 + 0];
  const float roy = rays[ray * 6 + 1];
  const float roz = rays[ray * 6 + 2];
  const float rdx = rays[ray * 6 + 3];
  const float rdy = rays[ray * 6 + 4];
  const float rdz = rays[ray * 6 + 5];
  const float b3v = b3[0];

  // a[k] = W1^T ro + b1, c[k] = W1^T rd  (fp32, register-resident, pair-packed)
  f32x2 ap[16], cp[16];
  #pragma unroll
  for (int s = 0; s < 4; ++s)
    #pragma unroll
    for (int p = 0; p < 4; ++p) {
      int k0 = 32 * s + 8 * q + 2 * p;
      int k1 = k0 + 1;
      float x0 = W1[k0], y0 = W1[HD + k0], z0 = W1[2 * HD + k0];
      float x1 = W1[k1], y1 = W1[HD + k1], z1 = W1[2 * HD + k1];
      f32x2 a, c;
      a.x = fmaf(x0, rox, fmaf(y0, roy, fmaf(z0, roz, b1[k0])));
      a.y = fmaf(x1, rox, fmaf(y1, roy, fmaf(z1, roz, b1[k1])));
      c.x = fmaf(x0, rdx, fmaf(y0, rdy, z0 * rdz));
      c.y = fmaf(x1, rdx, fmaf(y1, rdy, z1 * rdz));
      ap[4 * s + p] = a;
      cp[4 * s + p] = c;
    }

  // ---- sphere march (break when all 16 rays of the wave hit) ----
  float cd = T_NEAR;
  bool hit = false;
  #pragma unroll 1
  for (int it = 0; it < MARCH_N; ++it) {
    float d = sdf_fast(cd, w2f, ap, cp, sB2q, sW3q, b3v);
    bool nh = (d < HIT_EPS) && (cd >= T_NEAR) && (cd <= T_FAR);
    hit = hit || nh;
    cd = hit ? cd : cd + d;
    if (__ballot(!hit) == 0ull) break;
  }

  // ---- reflectance (exact fp32), split over 4 lane-quads ----
  const float ptx = fmaf(rdx, cd, rox);
  const float pty = fmaf(rdy, cd, roy);
  const float ptz = fmaf(rdz, cd, roz);
  float cr = 0.f, cg = 0.f, cb = 0.f;
  {
    int jb = q * 32;
    #pragma unroll 1
    for (int jj = 0; jj < 32; ++jj) {
      int j = jb + jj;
      float h = fmaf(R1[0 * HD + j], ptx,
                fmaf(R1[1 * HD + j], pty,
                fmaf(R1[2 * HD + j], ptz,
                fmaf(R1[3 * HD + j], rdx,
                fmaf(R1[4 * HD + j], rdy,
                fmaf(R1[5 * HD + j], rdz, rb1[j]))))));
      h = fmaxf(h, 0.f);
      cr = fmaf(h, R2[j * 3 + 0], cr);
      cg = fmaf(h, R2[j * 3 + 1], cg);
      cb = fmaf(h, R2[j * 3 + 2], cb);
    }
    cr += __shfl_xor(cr, 16); cr += __shfl_xor(cr, 32);
    cg += __shfl_xor(cg, 16); cg += __shfl_xor(cg, 32);
    cb += __shfl_xor(cb, 16); cb += __shfl_xor(cb, 32);
    cr += rb2[0]; cg += rb2[1]; cb += rb2[2];
  }

  // ---- tube scan: argmin of sdf over t = s*STEP, s = 0..32 ----
  float mn = sdf_fast(0.f, w2f, ap, cp, sB2q, sW3q, b3v);
  int idx = 0;
  float ts = 0.f;
  #pragma unroll 1
  for (int s = 1; s <= TP_N; ++s) {
    ts += STEP;                       // exact (65*s/1024, s<=32)
    float d = sdf_fast(ts, w2f, ap, cp, sB2q, sW3q, b3v);
    if (d < mn) { mn = d; idx = s; }
  }

  // ---- final tput at best t, hi/lo split ----
  const float tb = STEP * (float)idx;
  const float tput = sdf_precise(tb, lane, w2f, ap, cp, sB2q, sW3q, b3v, wlo);

  if (q == 0) {
    float4 o;
    o.x = hit ? cr : 0.f;
    o.y = hit ? cg : 0.f;
    o.z = hit ? cb : 0.f;
    o.w = -ALPHA_C * tput;
    ((float4*)out)[ray] = o;
  }
}

extern "C" void kernel_launch(void* const* d_in, const int* in_sizes, int n_in,
                              void* d_out, int out_size, void* d_ws, size_t ws_size,
                              hipStream_t stream) {
  const float* rays = (const float*)d_in[0];
  const float* W1  = (const float*)d_in[1];
  const float* b1  = (const float*)d_in[2];
  const float* W2  = (const float*)d_in[3];
  const float* b2  = (const float*)d_in[4];
  const float* W3  = (const float*)d_in[5];
  const float* b3  = (const float*)d_in[6];
  const float* R1  = (const float*)d_in[7];
  const float* rb1 = (const float*)d_in[8];
  const float* R2  = (const float*)d_in[9];
  const float* rb2 = (const float*)d_in[10];

  unsigned short* whi = (unsigned short*)d_ws;   // 32 KB
  unsigned short* wlo = whi + 128 * 128;         // 32 KB

  const int nrays = in_sizes[0] / 6;

  hipLaunchKernelGGL(pack_w2, dim3(64), dim3(256), 0, stream, W2, whi, wlo);
  hipLaunchKernelGGL(render, dim3(nrays / 64), dim3(256), 0, stream,
                     rays, W1, b1, b2, W3, b3, R1, rb1, R2, rb2,
                     whi, wlo, (float*)d_out, nrays);
}

// Round 5
// 3763.034 us; speedup vs baseline: 1.4598x; 1.4598x over previous
//
#include <hip/hip_runtime.h>

typedef __attribute__((ext_vector_type(8))) short bf16x8;
typedef __attribute__((ext_vector_type(4))) float f32x4;
typedef __attribute__((ext_vector_type(2))) float f32x2;

constexpr int   HD      = 128;
constexpr float T_NEAR  = 0.2f;
constexpr float T_FAR   = 2.0f;
constexpr float ALPHA_C = 100.0f;
constexpr int   MARCH_N = 32;
constexpr float HIT_EPS = 0.005f;
constexpr int   TP_N    = 32;
constexpr float STEP    = 0.0634765625f;  // (2.0 + 0.5*(2/32))/32, exact

// ---------- bf16 helpers ----------
__device__ __forceinline__ unsigned short f2bf(float x) {
  unsigned u = __float_as_uint(x);
  unsigned r = 0x7fffu + ((u >> 16) & 1u);
  return (unsigned short)((u + r) >> 16);
}

union U8 { bf16x8 v; uint4 u4; unsigned short us[8]; };

__device__ __forceinline__ f32x2 pk_fma(f32x2 a, f32x2 b, f32x2 c) {
  f32x2 d;
  asm("v_pk_fma_f32 %0, %1, %2, %3" : "=v"(d) : "v"(a), "v"(b), "v"(c));
  return d;
}

// {h.x,h.y} -> packed bf16 pair (round-half-up) with relu in bf16-bit domain.
__device__ __forceinline__ unsigned pack_relu_pair(f32x2 h) {
  unsigned u0 = __float_as_uint(h.x) + 0x8000u;
  unsigned u1 = __float_as_uint(h.y) + 0x8000u;
  unsigned w, r;
  asm("v_perm_b32 %0, %1, %2, %3" : "=v"(w) : "v"(u1), "v"(u0), "s"(0x07060302u));
  asm("v_pk_max_i16 %0, %1, %2" : "=v"(r) : "v"(w), "v"(0u));
  return r;
}

// ---------- setup kernel: pack W2^T into per-lane MFMA A-fragments ----------
__global__ void pack_w2(const float* __restrict__ W2,
                        unsigned short* __restrict__ hi,
                        unsigned short* __restrict__ lo) {
  int idx = blockIdx.x * 256 + threadIdx.x;     // 0..16383
  int j = idx & 7, l = (idx >> 3) & 63, t = (idx >> 9) & 7, s = idx >> 12;
  int m = 16 * t + (l & 15);
  int k = 32 * s + (l >> 4) * 8 + j;
  float w = W2[k * HD + m];
  unsigned short h = f2bf(w);
  float hf = __uint_as_float(((unsigned)h) << 16);
  hi[idx] = h;
  lo[idx] = f2bf(w - hf);
}

// ---------- dual-batch bf16 MFMA SDF eval: two independent chains ----------
__device__ __forceinline__ void sdf_fast2(float tA, float tB,
    const bf16x8 (&w2f)[4][8],
    const f32x2 (&apA)[16], const f32x2 (&cpA)[16],
    const f32x2 (&apB)[16], const f32x2 (&cpB)[16],
    const f32x4 (&b2f)[8], const float4* __restrict__ sW3q, float b3v,
    float& dA, float& dB)
{
  f32x2 tA2; tA2.x = tA; tA2.y = tA;
  f32x2 tB2; tB2.x = tB; tB2.y = tB;

  f32x4 accA[8], accB[8];
  #pragma unroll
  for (int u = 0; u < 8; ++u) { accA[u] = b2f[u]; accB[u] = b2f[u]; }

  #pragma unroll
  for (int s = 0; s < 4; ++s) {
    U8 BA, BB;
    BA.u4.x = pack_relu_pair(pk_fma(cpA[4*s+0], tA2, apA[4*s+0]));
    BB.u4.x = pack_relu_pair(pk_fma(cpB[4*s+0], tB2, apB[4*s+0]));
    BA.u4.y = pack_relu_pair(pk_fma(cpA[4*s+1], tA2, apA[4*s+1]));
    BB.u4.y = pack_relu_pair(pk_fma(cpB[4*s+1], tB2, apB[4*s+1]));
    BA.u4.z = pack_relu_pair(pk_fma(cpA[4*s+2], tA2, apA[4*s+2]));
    BB.u4.z = pack_relu_pair(pk_fma(cpB[4*s+2], tB2, apB[4*s+2]));
    BA.u4.w = pack_relu_pair(pk_fma(cpA[4*s+3], tA2, apA[4*s+3]));
    BB.u4.w = pack_relu_pair(pk_fma(cpB[4*s+3], tB2, apB[4*s+3]));
    #pragma unroll
    for (int u = 0; u < 8; ++u) {
      accA[u] = __builtin_amdgcn_mfma_f32_16x16x32_bf16(w2f[s][u], BA.v, accA[u], 0, 0, 0);
      accB[u] = __builtin_amdgcn_mfma_f32_16x16x32_bf16(w2f[s][u], BB.v, accB[u], 0, 0, 0);
    }
  }

  f32x2 z; z.x = 0.f; z.y = 0.f;
  f32x2 e0A = z, e1A = z, e2A = z, e3A = z;
  f32x2 e0B = z, e1B = z, e2B = z, e3B = z;
  #pragma unroll
  for (int u = 0; u < 8; ++u) {
    float4 wv = sW3q[u];
    f32x2 wa; wa.x = wv.x; wa.y = wv.y;
    f32x2 wb; wb.x = wv.z; wb.y = wv.w;
    f32x4 yA = accA[u], yB = accB[u];
    f32x2 loA; loA.x = fmaxf(yA.x, 0.f); loA.y = fmaxf(yA.y, 0.f);
    f32x2 hiA; hiA.x = fmaxf(yA.z, 0.f); hiA.y = fmaxf(yA.w, 0.f);
    f32x2 loB; loB.x = fmaxf(yB.x, 0.f); loB.y = fmaxf(yB.y, 0.f);
    f32x2 hiB; hiB.x = fmaxf(yB.z, 0.f); hiB.y = fmaxf(yB.w, 0.f);
    if (u & 1) {
      e2A = pk_fma(loA, wa, e2A); e3A = pk_fma(hiA, wb, e3A);
      e2B = pk_fma(loB, wa, e2B); e3B = pk_fma(hiB, wb, e3B);
    } else {
      e0A = pk_fma(loA, wa, e0A); e1A = pk_fma(hiA, wb, e1A);
      e0B = pk_fma(loB, wa, e0B); e1B = pk_fma(hiB, wb, e1B);
    }
  }
  float sA = (e0A.x + e0A.y) + (e1A.x + e1A.y) + ((e2A.x + e2A.y) + (e3A.x + e3A.y));
  float sB = (e0B.x + e0B.y) + (e1B.x + e1B.y) + ((e2B.x + e2B.y) + (e3B.x + e3B.y));
  float rA = __shfl_xor(sA, 16);
  float rB = __shfl_xor(sB, 16);
  sA += rA; sB += rB;
  sA += __shfl_xor(sA, 32);
  sB += __shfl_xor(sB, 32);
  dA = sA + b3v;
  dB = sB + b3v;
}

// ---------- hi/lo-split precise eval (x100 tput channel), slim registers ----------
__device__ float sdf_precise(float t, int lane,
    const bf16x8 (&w2f)[4][8], const f32x2 (&ap)[16], const f32x2 (&cp)[16],
    const f32x4 (&b2f)[8], const float4* __restrict__ sW3q, float b3v,
    const unsigned short* __restrict__ wlo)
{
  const bf16x8* wloF = (const bf16x8*)wlo;
  f32x4 acc[8];
  #pragma unroll
  for (int u = 0; u < 8; ++u) acc[u] = b2f[u];

  #pragma unroll
  for (int s = 0; s < 4; ++s) {
    U8 HH, HL;
    #pragma unroll
    for (int p = 0; p < 4; ++p) {
      float h0 = fmaxf(fmaf(cp[4*s+p].x, t, ap[4*s+p].x), 0.f);
      float h1 = fmaxf(fmaf(cp[4*s+p].y, t, ap[4*s+p].y), 0.f);
      unsigned short hb0 = f2bf(h0), hb1 = f2bf(h1);
      float r0 = h0 - __uint_as_float(((unsigned)hb0) << 16);
      float r1 = h1 - __uint_as_float(((unsigned)hb1) << 16);
      HH.us[2*p]     = hb0;      HH.us[2*p + 1] = hb1;
      HL.us[2*p]     = f2bf(r0); HL.us[2*p + 1] = f2bf(r1);
    }
    #pragma unroll
    for (int u = 0; u < 8; ++u) {
      bf16x8 wl = wloF[(s * 8 + u) * 64 + lane];
      acc[u] = __builtin_amdgcn_mfma_f32_16x16x32_bf16(w2f[s][u], HH.v, acc[u], 0, 0, 0);
      acc[u] = __builtin_amdgcn_mfma_f32_16x16x32_bf16(wl,        HH.v, acc[u], 0, 0, 0);
      acc[u] = __builtin_amdgcn_mfma_f32_16x16x32_bf16(w2f[s][u], HL.v, acc[u], 0, 0, 0);
    }
  }

  f32x2 z; z.x = 0.f; z.y = 0.f;
  f32x2 e0 = z, e1 = z, e2 = z, e3 = z;
  #pragma unroll
  for (int u = 0; u < 8; ++u) {
    float4 wv = sW3q[u];
    f32x2 wa; wa.x = wv.x; wa.y = wv.y;
    f32x2 wb; wb.x = wv.z; wb.y = wv.w;
    f32x4 y = acc[u];
    f32x2 lo; lo.x = fmaxf(y.x, 0.f); lo.y = fmaxf(y.y, 0.f);
    f32x2 hi; hi.x = fmaxf(y.z, 0.f); hi.y = fmaxf(y.w, 0.f);
    if (u & 1) { e2 = pk_fma(lo, wa, e2); e3 = pk_fma(hi, wb, e3); }
    else       { e0 = pk_fma(lo, wa, e0); e1 = pk_fma(hi, wb, e1); }
  }
  float d = (e0.x + e0.y) + (e1.x + e1.y) + ((e2.x + e2.y) + (e3.x + e3.y));
  d += __shfl_xor(d, 16);
  d += __shfl_xor(d, 32);
  return d + b3v;
}

// ---------- exact fp32 reflectance, quad-split + shfl reduce ----------
__device__ __forceinline__ void refl_eval(
    float ptx, float pty, float ptz, float rdx, float rdy, float rdz, int q,
    const float* __restrict__ R1, const float* __restrict__ rb1,
    const float* __restrict__ R2, const float* __restrict__ rb2,
    float& cr, float& cg, float& cb)
{
  cr = 0.f; cg = 0.f; cb = 0.f;
  int jb = q * 32;
  #pragma unroll 1
  for (int jj = 0; jj < 32; ++jj) {
    int j = jb + jj;
    float h = fmaf(R1[0 * HD + j], ptx,
              fmaf(R1[1 * HD + j], pty,
              fmaf(R1[2 * HD + j], ptz,
              fmaf(R1[3 * HD + j], rdx,
              fmaf(R1[4 * HD + j], rdy,
              fmaf(R1[5 * HD + j], rdz, rb1[j]))))));
    h = fmaxf(h, 0.f);
    cr = fmaf(h, R2[j * 3 + 0], cr);
    cg = fmaf(h, R2[j * 3 + 1], cg);
    cb = fmaf(h, R2[j * 3 + 2], cb);
  }
  cr += __shfl_xor(cr, 16); cr += __shfl_xor(cr, 32);
  cg += __shfl_xor(cg, 16); cg += __shfl_xor(cg, 32);
  cb += __shfl_xor(cb, 16); cb += __shfl_xor(cb, 32);
  cr += rb2[0]; cg += rb2[1]; cb += rb2[2];
}

// ---------- main: 1 wave = 32 rays (2 batches of 16), 1 wave/SIMD ----------
__global__ __launch_bounds__(256, 1)
void render(const float* __restrict__ rays,
            const float* __restrict__ W1, const float* __restrict__ b1,
            const float* __restrict__ b2, const float* __restrict__ W3,
            const float* __restrict__ b3,
            const float* __restrict__ R1, const float* __restrict__ rb1,
            const float* __restrict__ R2, const float* __restrict__ rb2,
            const unsigned short* __restrict__ whi,
            const unsigned short* __restrict__ wlo,
            float* __restrict__ out, int nrays)
{
  // W3 broadcast table per quad (0.5 KB)
  __shared__ float4 sW3[32];
  const int tid = threadIdx.x;
  if (tid < 32) {
    int u = tid & 7, qq = tid >> 3;
    sW3[tid] = *(const float4*)(W3 + 16 * u + 4 * qq);
  }
  __syncthreads();

  const int lane = tid & 63;
  const int q    = lane >> 4;
  const int wv   = tid >> 6;
  const int rayA = blockIdx.x * 128 + wv * 32 + (lane & 15);
  const int rayB = rayA + 16;
  const float4* sW3q = sW3 + q * 8;

  // W2^T hi fragments resident: 128 VGPRs
  bf16x8 w2f[4][8];
  const bf16x8* whiF = (const bf16x8*)whi;
  #pragma unroll
  for (int s = 0; s < 4; ++s)
    #pragma unroll
    for (int u = 0; u < 8; ++u)
      w2f[s][u] = whiF[(s * 8 + u) * 64 + lane];

  const float roxA = rays[rayA * 6 + 0], royA = rays[rayA * 6 + 1], rozA = rays[rayA * 6 + 2];
  const float rdxA = rays[rayA * 6 + 3], rdyA = rays[rayA * 6 + 4], rdzA = rays[rayA * 6 + 5];
  const float roxB = rays[rayB * 6 + 0], royB = rays[rayB * 6 + 1], rozB = rays[rayB * 6 + 2];
  const float rdxB = rays[rayB * 6 + 3], rdyB = rays[rayB * 6 + 4], rdzB = rays[rayB * 6 + 5];
  const float b3v = b3[0];

  // per-batch a/c (fp32, register-resident); W1 loads shared across batches
  f32x2 apA[16], cpA[16], apB[16], cpB[16];
  #pragma unroll
  for (int s = 0; s < 4; ++s)
    #pragma unroll
    for (int p = 0; p < 4; ++p) {
      int k0 = 32 * s + 8 * q + 2 * p;
      int k1 = k0 + 1;
      float x0 = W1[k0], y0 = W1[HD + k0], z0 = W1[2 * HD + k0], bk0 = b1[k0];
      float x1 = W1[k1], y1 = W1[HD + k1], z1 = W1[2 * HD + k1], bk1 = b1[k1];
      f32x2 a, c;
      a.x = fmaf(x0, roxA, fmaf(y0, royA, fmaf(z0, rozA, bk0)));
      a.y = fmaf(x1, roxA, fmaf(y1, royA, fmaf(z1, rozA, bk1)));
      c.x = fmaf(x0, rdxA, fmaf(y0, rdyA, z0 * rdzA));
      c.y = fmaf(x1, rdxA, fmaf(y1, rdyA, z1 * rdzA));
      apA[4 * s + p] = a; cpA[4 * s + p] = c;
      a.x = fmaf(x0, roxB, fmaf(y0, royB, fmaf(z0, rozB, bk0)));
      a.y = fmaf(x1, roxB, fmaf(y1, royB, fmaf(z1, rozB, bk1)));
      c.x = fmaf(x0, rdxB, fmaf(y0, rdyB, z0 * rdzB));
      c.y = fmaf(x1, rdxB, fmaf(y1, rdyB, z1 * rdzB));
      apB[4 * s + p] = a; cpB[4 * s + p] = c;
    }

  // b2 as MFMA C-init fragments (32 VGPRs, shared by both batches)
  f32x4 b2f[8];
  #pragma unroll
  for (int u = 0; u < 8; ++u) {
    int n0 = 16 * u + 4 * q;
    float4 bb = *(const float4*)(b2 + n0);
    f32x4 bv; bv.x = bb.x; bv.y = bb.y; bv.z = bb.z; bv.w = bb.w;
    b2f[u] = bv;
  }

  // ---- sphere march: both batches interleaved ----
  float cdA = T_NEAR, cdB = T_NEAR;
  bool hitA = false, hitB = false;
  #pragma unroll 1
  for (int it = 0; it < MARCH_N; ++it) {
    float dA, dB;
    sdf_fast2(cdA, cdB, w2f, apA, cpA, apB, cpB, b2f, sW3q, b3v, dA, dB);
    bool nhA = (dA < HIT_EPS) && (cdA >= T_NEAR) && (cdA <= T_FAR);
    bool nhB = (dB < HIT_EPS) && (cdB >= T_NEAR) && (cdB <= T_FAR);
    hitA = hitA || nhA;  hitB = hitB || nhB;
    cdA = hitA ? cdA : cdA + dA;
    cdB = hitB ? cdB : cdB + dB;
    if (__ballot((!hitA) || (!hitB)) == 0ull) break;
  }

  // ---- reflectance (exact fp32) per batch ----
  float crA, cgA, cbA, crB, cgB, cbB;
  refl_eval(fmaf(rdxA, cdA, roxA), fmaf(rdyA, cdA, royA), fmaf(rdzA, cdA, rozA),
            rdxA, rdyA, rdzA, q, R1, rb1, R2, rb2, crA, cgA, cbA);
  refl_eval(fmaf(rdxB, cdB, roxB), fmaf(rdyB, cdB, royB), fmaf(rdzB, cdB, rozB),
            rdxB, rdyB, rdzB, q, R1, rb1, R2, rb2, crB, cgB, cbB);

  // ---- tube scan: t shared by batches; per-batch argmin ----
  float mnA, mnB;
  sdf_fast2(0.f, 0.f, w2f, apA, cpA, apB, cpB, b2f, sW3q, b3v, mnA, mnB);
  int idxA = 0, idxB = 0;
  float ts = 0.f;
  #pragma unroll 1
  for (int s = 1; s <= TP_N; ++s) {
    ts += STEP;                       // exact (65*s/1024, s<=32)
    float dA, dB;
    sdf_fast2(ts, ts, w2f, apA, cpA, apB, cpB, b2f, sW3q, b3v, dA, dB);
    if (dA < mnA) { mnA = dA; idxA = s; }
    if (dB < mnB) { mnB = dB; idxB = s; }
  }

  // ---- final tput per batch, hi/lo split ----
  const float tputA = sdf_precise(STEP * (float)idxA, lane, w2f, apA, cpA, b2f, sW3q, b3v, wlo);
  const float tputB = sdf_precise(STEP * (float)idxB, lane, w2f, apB, cpB, b2f, sW3q, b3v, wlo);

  if (q == 0) {
    float4 o;
    o.x = hitA ? crA : 0.f;
    o.y = hitA ? cgA : 0.f;
    o.z = hitA ? cbA : 0.f;
    o.w = -ALPHA_C * tputA;
    ((float4*)out)[rayA] = o;
  } else if (q == 1) {
    float4 o;
    o.x = hitB ? crB : 0.f;
    o.y = hitB ? cgB : 0.f;
    o.z = hitB ? cbB : 0.f;
    o.w = -ALPHA_C * tputB;
    ((float4*)out)[rayB] = o;
  }
}

extern "C" void kernel_launch(void* const* d_in, const int* in_sizes, int n_in,
                              void* d_out, int out_size, void* d_ws, size_t ws_size,
                              hipStream_t stream) {
  const float* rays = (const float*)d_in[0];
  const float* W1  = (const float*)d_in[1];
  const float* b1  = (const float*)d_in[2];
  const float* W2  = (const float*)d_in[3];
  const float* b2  = (const float*)d_in[4];
  const float* W3  = (const float*)d_in[5];
  const float* b3  = (const float*)d_in[6];
  const float* R1  = (const float*)d_in[7];
  const float* rb1 = (const float*)d_in[8];
  const float* R2  = (const float*)d_in[9];
  const float* rb2 = (const float*)d_in[10];

  unsigned short* whi = (unsigned short*)d_ws;   // 32 KB
  unsigned short* wlo = whi + 128 * 128;         // 32 KB

  const int nrays = in_sizes[0] / 6;

  hipLaunchKernelGGL(pack_w2, dim3(64), dim3(256), 0, stream, W2, whi, wlo);
  hipLaunchKernelGGL(render, dim3(nrays / 128), dim3(256), 0, stream,
                     rays, W1, b1, b2, W3, b3, R1, rb1, R2, rb2,
                     whi, wlo, (float*)d_out, nrays);
}